// Round 4
// baseline (915.314 us; speedup 1.0000x reference)
//
#include <hip/hip_runtime.h>
#include <hip/hip_bf16.h>

#define B_TOK 16384
#define D_MOD 2048
#define N_EXP 16
#define R_RK  128
#define MAXTILES 272              // ceil-aligned (B*2 + 16*127)/128 <= 272
#define MAXROWS (MAXTILES * 128)  // 34816

typedef __bf16 bf16x8 __attribute__((ext_vector_type(8)));
typedef float  f32x4  __attribute__((ext_vector_type(4)));
typedef unsigned short u16x8 __attribute__((ext_vector_type(8)));

// ---------- helpers ----------
__device__ __forceinline__ unsigned short f2bf_bits(float f) {
  unsigned u = __float_as_uint(f);
  u += 0x7fffu + ((u >> 16) & 1u);   // RNE
  return (unsigned short)(u >> 16);
}
__device__ __forceinline__ float bf2f(unsigned short b) {
  return __uint_as_float((unsigned)b << 16);
}

__device__ __forceinline__ void gl2lds16(const void* g, void* l) {
  __builtin_amdgcn_global_load_lds((__attribute__((address_space(1))) void*)(void*)g,
                                   (__attribute__((address_space(3))) void*)l, 16, 0, 0);
}

// ---------- init: counts + pad rows ----------
__global__ void init_kernel(int* counts, int* tok_row, float* w_row) {
  int i = blockIdx.x * 256 + threadIdx.x;
  if (i < N_EXP) counts[i] = 0;
  if (i < MAXROWS) { tok_row[i] = 0; w_row[i] = 0.0f; }
}

// ---------- merged f32->bf16 conversions (x, Wenc, U, V) ----------
#define CVT_N0 (B_TOK * D_MOD / 4)          // 8388608 float4s of x
#define CVT_N1 (D_MOD * D_MOD / 4)          // 1048576 Wenc
#define CVT_N2 (N_EXP * R_RK * D_MOD / 4)   // 1048576 U
#define CVT_N3 (N_EXP * D_MOD * R_RK / 4)   // 1048576 V
__global__ void cvt_all(const float* __restrict__ x, const float* __restrict__ Wenc,
                        const float* __restrict__ U, const float* __restrict__ V,
                        unsigned short* __restrict__ xb, unsigned short* __restrict__ Wencb,
                        unsigned short* __restrict__ Ub, unsigned short* __restrict__ Vb) {
  int i = blockIdx.x * 256 + threadIdx.x;
  const float4* s; ushort4* d; int j;
  if (i < CVT_N0) { s = (const float4*)x; d = (ushort4*)xb; j = i; }
  else if (i < CVT_N0 + CVT_N1) { s = (const float4*)Wenc; d = (ushort4*)Wencb; j = i - CVT_N0; }
  else if (i < CVT_N0 + CVT_N1 + CVT_N2) { s = (const float4*)U; d = (ushort4*)Ub; j = i - CVT_N0 - CVT_N1; }
  else if (i < CVT_N0 + CVT_N1 + CVT_N2 + CVT_N3) { s = (const float4*)V; d = (ushort4*)Vb; j = i - CVT_N0 - CVT_N1 - CVT_N2; }
  else return;
  float4 v = s[j];
  ushort4 o;
  o.x = f2bf_bits(v.x); o.y = f2bf_bits(v.y);
  o.z = f2bf_bits(v.z); o.w = f2bf_bits(v.w);
  d[j] = o;
}

// ---------- fp64 routing pipeline ----------
__global__ void wgeff_partial(const float* __restrict__ Wg, const float* __restrict__ Wenc,
                              double* __restrict__ part) {
  int k = blockIdx.x * 256 + threadIdx.x;  // grid.x = 8
  int dc = blockIdx.y;                     // 0..31
  double acc[N_EXP];
#pragma unroll
  for (int m = 0; m < N_EXP; m++) acc[m] = 0.0;
  for (int d = dc * 64; d < dc * 64 + 64; ++d) {
    double we = (double)Wenc[(size_t)d * D_MOD + k];
#pragma unroll
    for (int m = 0; m < N_EXP; m++) acc[m] += (double)Wg[m * D_MOD + d] * we;
  }
#pragma unroll
  for (int m = 0; m < N_EXP; m++) part[((size_t)dc * N_EXP + m) * D_MOD + k] = acc[m];
}

__global__ void wgeff_reduce(const double* __restrict__ part, float* __restrict__ WgEffF) {
  int k = blockIdx.x * 256 + threadIdx.x;  // grid.x = 8
  int m = blockIdx.y;                      // 0..15
  double s = 0.0;
#pragma unroll
  for (int dc = 0; dc < 32; dc++) s += part[((size_t)dc * N_EXP + m) * D_MOD + k];
  WgEffF[(size_t)m * D_MOD + k] = (float)s;
}

__global__ void bias_kernel(const float* __restrict__ benc, const float* __restrict__ Wg,
                            double* __restrict__ biasd) {
  int m = blockIdx.x;
  double s = 0.0;
  for (int d = threadIdx.x; d < D_MOD; d += 256)
    s += (double)benc[d] * (double)Wg[m * D_MOD + d];
  __shared__ double red[256];
  red[threadIdx.x] = s;
  __syncthreads();
  for (int st = 128; st; st >>= 1) {
    if (threadIdx.x < st) red[threadIdx.x] += red[threadIdx.x + st];
    __syncthreads();
  }
  if (threadIdx.x == 0) biasd[m] = red[0];
}

// logits (fp64 accum) + top-2 + softmax + counts. (proven fast in R2, unchanged)
__global__ __launch_bounds__(256, 2) void routing_kernel(
    const float* __restrict__ x, const float* __restrict__ WgEffF, const double* __restrict__ biasd,
    int* __restrict__ counts, int* __restrict__ tke, float* __restrict__ tkw) {
  __shared__ float xs[2][16 * 256];
  __shared__ float wgs[2][16 * 256];
  const int tid = threadIdx.x;
  const int wv = tid >> 6, lane = tid & 63;
  const int b0 = blockIdx.x * 16;

  double acc[4][N_EXP];
#pragma unroll
  for (int t = 0; t < 4; t++)
#pragma unroll
    for (int m = 0; m < N_EXP; m++) acc[t][m] = 0.0;

  auto stage = [&](int buf, int ch) {
#pragma unroll
    for (int r = 0; r < 8; r++) {
      int row = wv * 8 + r;
      const float* g;
      float* l;
      if (row < 16) { g = x + (size_t)(b0 + row) * D_MOD + ch * 256; l = &xs[buf][row * 256]; }
      else          { g = WgEffF + (size_t)(row - 16) * D_MOD + ch * 256; l = &wgs[buf][(row - 16) * 256]; }
      gl2lds16(g + (size_t)lane * 4, l);
    }
  };

  stage(0, 0);
  for (int ch = 0; ch < 8; ch++) {
    __syncthreads();
    if (ch < 7) stage((ch + 1) & 1, ch + 1);
    const float* xb = &xs[ch & 1][0];
    const float* wb = &wgs[ch & 1][0];
#pragma unroll
    for (int i = 0; i < 2; i++) {
      int dl = i * 128 + lane * 2;
      float2 xv[4];
#pragma unroll
      for (int t = 0; t < 4; t++) xv[t] = *(const float2*)&xb[(wv * 4 + t) * 256 + dl];
#pragma unroll
      for (int m = 0; m < N_EXP; m++) {
        float2 wv2 = *(const float2*)&wb[m * 256 + dl];
        double w0 = (double)wv2.x, w1 = (double)wv2.y;
#pragma unroll
        for (int t = 0; t < 4; t++) {
          acc[t][m] = fma((double)xv[t].x, w0, acc[t][m]);
          acc[t][m] = fma((double)xv[t].y, w1, acc[t][m]);
        }
      }
    }
  }

#pragma unroll
  for (int t = 0; t < 4; t++)
#pragma unroll
    for (int m = 0; m < N_EXP; m++) {
      double v = acc[t][m];
#pragma unroll
      for (int off = 32; off; off >>= 1) v += __shfl_xor(v, off);
      acc[t][m] = v;
    }

#pragma unroll
  for (int t = 0; t < 4; t++) {
    if (lane == t) {
      int b = b0 + wv * 4 + t;
      double vm[N_EXP];
#pragma unroll
      for (int m = 0; m < N_EXP; m++) vm[m] = acc[t][m] + biasd[m];  // TAU = 1.0
      double v1 = vm[0]; int i1 = 0;
#pragma unroll
      for (int m = 1; m < N_EXP; m++) if (vm[m] > v1) { v1 = vm[m]; i1 = m; }
      double v2 = -1e300; int i2 = 0;
#pragma unroll
      for (int m = 0; m < N_EXP; m++) if (m != i1 && vm[m] > v2) { v2 = vm[m]; i2 = m; }
      double ex = exp(v2 - v1);
      double den = 1.0 + ex;
      float w1 = (float)(1.0 / den), w2 = (float)(ex / den);
      if (!(w1 > 1e-12f)) w1 = 0.0f;
      if (!(w2 > 1e-12f)) w2 = 0.0f;
      tke[b * 2] = i1; tke[b * 2 + 1] = i2;
      tkw[b * 2] = w1; tkw[b * 2 + 1] = w2;
      atomicAdd(&counts[i1], 1);
      atomicAdd(&counts[i2], 1);
    }
  }
}

__global__ void bases_kernel(const int* __restrict__ counts, int* cursor, int* tile2e) {
  if (threadIdx.x == 0) {
    int b = 0;
    for (int e = 0; e < N_EXP; e++) {
      cursor[e] = b;
      int nt = (counts[e] + 127) >> 7;
      for (int t = 0; t < nt; t++) tile2e[b / 128 + t] = e;
      b += nt * 128;
    }
    for (int rt = b / 128; rt < MAXTILES; rt++) tile2e[rt] = -1;
  }
}

__global__ void scatter_kernel(const int* __restrict__ tke, const float* __restrict__ tkw,
                               const float* __restrict__ gamma, int* cursor,
                               int* __restrict__ tok_row, float* __restrict__ w_row,
                               int* __restrict__ pos) {
  int b = blockIdx.x * 256 + threadIdx.x;
  if (b >= B_TOK) return;
#pragma unroll
  for (int s = 0; s < 2; s++) {
    int e = tke[b * 2 + s];
    float w = tkw[b * 2 + s] * gamma[e];
    int p = atomicAdd(&cursor[e], 1);
    tok_row[p] = b; w_row[p] = w;
    pos[b * 2 + s] = p;
  }
}

// ============ GEMM common structure (T3+T4): 3-slot LDS ring, prefetch t+2,
// counted s_waitcnt vmcnt(4) + raw s_barrier (never drain-to-0 in loop).
// mfma operands SWAPPED (bf,af): lane holds one row (l16) x 4 consecutive cols
// (q*4+reg) per fragment -> ushort4 8B epilogue stores (4x fewer, bit-identical).

// ---------- GEMM 1: encb = bf16(x @ Wenc^T) ----------
__global__ __launch_bounds__(256) void gemm_enc(
    const unsigned short* __restrict__ A,   // x_bf16 [B, D]
    const unsigned short* __restrict__ Bm,  // Wenc_bf16 [D, D]
    unsigned short* __restrict__ encb) {    // [B, D]
  __shared__ unsigned short lA[3][128 * 32];  // 24 KB
  __shared__ unsigned short lB[3][128 * 32];  // 24 KB
  const int tid = threadIdx.x;
  const int wv = tid >> 6, lane = tid & 63;
  const int q = lane >> 4, l16 = lane & 15;
  const int tm = blockIdx.x, tn = blockIdx.y;

  const int srow = wv * 16 + (lane >> 2);
  const int scol = (lane & 3) * 8;
  const unsigned short* ga0 = A + (size_t)(tm * 128 + srow) * D_MOD + scol;
  const unsigned short* ga1 = ga0 + (size_t)64 * D_MOD;
  const unsigned short* gb0 = Bm + (size_t)(tn * 128 + srow) * D_MOD + scol;
  const unsigned short* gb1 = gb0 + (size_t)64 * D_MOD;

  auto stage = [&](int s, int k0) {
    unsigned short* la = &lA[0][0] + s * (128 * 32);
    unsigned short* lb = &lB[0][0] + s * (128 * 32);
    gl2lds16(ga0 + k0, la + (wv * 16) * 32);
    gl2lds16(ga1 + k0, la + (wv * 16 + 64) * 32);
    gl2lds16(gb0 + k0, lb + (wv * 16) * 32);
    gl2lds16(gb1 + k0, lb + (wv * 16 + 64) * 32);
  };

  const int wm = (wv & 1) * 64, wn = (wv >> 1) * 64;
  f32x4 acc[4][4] = {};

  stage(0, 0);
  stage(1, 32);
  asm volatile("s_waitcnt vmcnt(4)" ::: "memory");
  __builtin_amdgcn_s_barrier();
  asm volatile("" ::: "memory");

  const int nk = D_MOD / 32;  // 64
  int cur = 0;
  for (int t = 0; t < nk; ++t) {
    int nxt = cur + 2; if (nxt >= 3) nxt -= 3;
    const bool pf = (t + 2 < nk);
    if (pf) stage(nxt, (t + 2) * 32);
    const unsigned short* la = &lA[0][0] + cur * (128 * 32);
    const unsigned short* lb = &lB[0][0] + cur * (128 * 32);
    bf16x8 af[4], bf[4];
#pragma unroll
    for (int i = 0; i < 4; i++) af[i] = *(const bf16x8*)&la[(wm + i * 16 + l16) * 32 + q * 8];
#pragma unroll
    for (int j = 0; j < 4; j++) bf[j] = *(const bf16x8*)&lb[(wn + j * 16 + l16) * 32 + q * 8];
#pragma unroll
    for (int i = 0; i < 4; i++)
#pragma unroll
      for (int j = 0; j < 4; j++)
        acc[i][j] = __builtin_amdgcn_mfma_f32_16x16x32_bf16(bf[j], af[i], acc[i][j], 0, 0, 0);
    if (pf) asm volatile("s_waitcnt vmcnt(4)" ::: "memory");
    else    asm volatile("s_waitcnt vmcnt(0)" ::: "memory");
    __builtin_amdgcn_s_barrier();
    asm volatile("" ::: "memory");
    cur = cur + 1; if (cur == 3) cur = 0;
  }

#pragma unroll
  for (int i = 0; i < 4; i++) {
    int row = tm * 128 + wm + i * 16 + l16;
#pragma unroll
    for (int j = 0; j < 4; j++) {
      int col = tn * 128 + wn + j * 16 + q * 4;
      ushort4 o;
      o.x = f2bf_bits(acc[i][j][0]); o.y = f2bf_bits(acc[i][j][1]);
      o.z = f2bf_bits(acc[i][j][2]); o.w = f2bf_bits(acc[i][j][3]);
      *(ushort4*)&encb[(size_t)row * D_MOD + col] = o;
    }
  }
}

// ---------- GEMM 2: S = silu(enc_gathered @ U[e]^T) * (w*gamma) ----------
__global__ __launch_bounds__(256) void gemm_up(
    const unsigned short* __restrict__ encb,  // [B, D]
    const unsigned short* __restrict__ Ub,    // [M, R, D]
    const int* __restrict__ tile2e, const int* __restrict__ tok_row,
    const float* __restrict__ w_row,
    unsigned short* __restrict__ S) {         // [MAXROWS, R]
  const int rt = blockIdx.x;
  const int e = tile2e[rt];
  if (e < 0) return;
  __shared__ unsigned short lA[3][128 * 32];
  __shared__ unsigned short lB[3][128 * 32];
  const int tid = threadIdx.x;
  const int wv = tid >> 6, lane = tid & 63;
  const int q = lane >> 4, l16 = lane & 15;

  const int srow = wv * 16 + (lane >> 2);
  const int scol = (lane & 3) * 8;
  const int tok0 = tok_row[rt * 128 + srow];
  const int tok1 = tok_row[rt * 128 + srow + 64];
  const unsigned short* ga0 = encb + (size_t)tok0 * D_MOD + scol;
  const unsigned short* ga1 = encb + (size_t)tok1 * D_MOD + scol;
  const unsigned short* gbase = Ub + (size_t)e * R_RK * D_MOD;
  const unsigned short* gb0 = gbase + (size_t)srow * D_MOD + scol;
  const unsigned short* gb1 = gb0 + (size_t)64 * D_MOD;

  auto stage = [&](int s, int k0) {
    unsigned short* la = &lA[0][0] + s * (128 * 32);
    unsigned short* lb = &lB[0][0] + s * (128 * 32);
    gl2lds16(ga0 + k0, la + (wv * 16) * 32);
    gl2lds16(ga1 + k0, la + (wv * 16 + 64) * 32);
    gl2lds16(gb0 + k0, lb + (wv * 16) * 32);
    gl2lds16(gb1 + k0, lb + (wv * 16 + 64) * 32);
  };

  const int wm = (wv & 1) * 64, wn = (wv >> 1) * 64;
  f32x4 acc[4][4] = {};

  stage(0, 0);
  stage(1, 32);
  asm volatile("s_waitcnt vmcnt(4)" ::: "memory");
  __builtin_amdgcn_s_barrier();
  asm volatile("" ::: "memory");

  const int nk = D_MOD / 32;  // 64
  int cur = 0;
  for (int t = 0; t < nk; ++t) {
    int nxt = cur + 2; if (nxt >= 3) nxt -= 3;
    const bool pf = (t + 2 < nk);
    if (pf) stage(nxt, (t + 2) * 32);
    const unsigned short* la = &lA[0][0] + cur * (128 * 32);
    const unsigned short* lb = &lB[0][0] + cur * (128 * 32);
    bf16x8 af[4], bf[4];
#pragma unroll
    for (int i = 0; i < 4; i++) af[i] = *(const bf16x8*)&la[(wm + i * 16 + l16) * 32 + q * 8];
#pragma unroll
    for (int j = 0; j < 4; j++) bf[j] = *(const bf16x8*)&lb[(wn + j * 16 + l16) * 32 + q * 8];
#pragma unroll
    for (int i = 0; i < 4; i++)
#pragma unroll
      for (int j = 0; j < 4; j++)
        acc[i][j] = __builtin_amdgcn_mfma_f32_16x16x32_bf16(bf[j], af[i], acc[i][j], 0, 0, 0);
    if (pf) asm volatile("s_waitcnt vmcnt(4)" ::: "memory");
    else    asm volatile("s_waitcnt vmcnt(0)" ::: "memory");
    __builtin_amdgcn_s_barrier();
    asm volatile("" ::: "memory");
    cur = cur + 1; if (cur == 3) cur = 0;
  }

#pragma unroll
  for (int i = 0; i < 4; i++) {
    int prow = rt * 128 + wm + i * 16 + l16;
    float wr = w_row[prow];  // pad rows have w=0 -> write 0
#pragma unroll
    for (int j = 0; j < 4; j++) {
      int col = wn + j * 16 + q * 4;
      ushort4 o;
      float v0 = acc[i][j][0], v1 = acc[i][j][1], v2 = acc[i][j][2], v3 = acc[i][j][3];
      o.x = f2bf_bits((v0 / (1.0f + __expf(-v0))) * wr);
      o.y = f2bf_bits((v1 / (1.0f + __expf(-v1))) * wr);
      o.z = f2bf_bits((v2 / (1.0f + __expf(-v2))) * wr);
      o.w = f2bf_bits((v3 / (1.0f + __expf(-v3))) * wr);
      *(ushort4*)&S[(size_t)prow * R_RK + col] = o;
    }
  }
}

// ---------- GEMM 3: Drows = S @ V[e]^T (dense per-slot delta rows, bf16) ----------
__global__ __launch_bounds__(256) void gemm_down(
    const unsigned short* __restrict__ S,   // [MAXROWS, R]
    const unsigned short* __restrict__ Vb,  // [M, D, R]
    const int* __restrict__ tile2e,
    unsigned short* __restrict__ Drows) {   // [MAXROWS, D]
  const int rt = blockIdx.x, ct = blockIdx.y;
  const int e = tile2e[rt];
  if (e < 0) return;
  __shared__ unsigned short lA[3][128 * 32];
  __shared__ unsigned short lB[3][128 * 32];
  const int tid = threadIdx.x;
  const int wv = tid >> 6, lane = tid & 63;
  const int q = lane >> 4, l16 = lane & 15;

  const int srow = wv * 16 + (lane >> 2);
  const int scol = (lane & 3) * 8;
  const unsigned short* ga0 = S + (size_t)(rt * 128 + srow) * R_RK + scol;
  const unsigned short* ga1 = ga0 + (size_t)64 * R_RK;
  const unsigned short* gb0 = Vb + ((size_t)e * D_MOD + ct * 128 + srow) * R_RK + scol;
  const unsigned short* gb1 = gb0 + (size_t)64 * R_RK;

  auto stage = [&](int s, int k0) {
    unsigned short* la = &lA[0][0] + s * (128 * 32);
    unsigned short* lb = &lB[0][0] + s * (128 * 32);
    gl2lds16(ga0 + k0, la + (wv * 16) * 32);
    gl2lds16(ga1 + k0, la + (wv * 16 + 64) * 32);
    gl2lds16(gb0 + k0, lb + (wv * 16) * 32);
    gl2lds16(gb1 + k0, lb + (wv * 16 + 64) * 32);
  };

  const int wm = (wv & 1) * 64, wn = (wv >> 1) * 64;
  f32x4 acc[4][4] = {};

  stage(0, 0);
  stage(1, 32);
  asm volatile("s_waitcnt vmcnt(4)" ::: "memory");
  __builtin_amdgcn_s_barrier();
  asm volatile("" ::: "memory");

  const int nk = R_RK / 32;  // 4
  int cur = 0;
  for (int t = 0; t < nk; ++t) {
    int nxt = cur + 2; if (nxt >= 3) nxt -= 3;
    const bool pf = (t + 2 < nk);
    if (pf) stage(nxt, (t + 2) * 32);
    const unsigned short* la = &lA[0][0] + cur * (128 * 32);
    const unsigned short* lb = &lB[0][0] + cur * (128 * 32);
    bf16x8 af[4], bf[4];
#pragma unroll
    for (int i = 0; i < 4; i++) af[i] = *(const bf16x8*)&la[(wm + i * 16 + l16) * 32 + q * 8];
#pragma unroll
    for (int j = 0; j < 4; j++) bf[j] = *(const bf16x8*)&lb[(wn + j * 16 + l16) * 32 + q * 8];
#pragma unroll
    for (int i = 0; i < 4; i++)
#pragma unroll
      for (int j = 0; j < 4; j++)
        acc[i][j] = __builtin_amdgcn_mfma_f32_16x16x32_bf16(bf[j], af[i], acc[i][j], 0, 0, 0);
    if (pf) asm volatile("s_waitcnt vmcnt(4)" ::: "memory");
    else    asm volatile("s_waitcnt vmcnt(0)" ::: "memory");
    __builtin_amdgcn_s_barrier();
    asm volatile("" ::: "memory");
    cur = cur + 1; if (cur == 3) cur = 0;
  }

#pragma unroll
  for (int i = 0; i < 4; i++) {
    int prow = rt * 128 + wm + i * 16 + l16;
    size_t obase = (size_t)prow * D_MOD + ct * 128 + wn;
#pragma unroll
    for (int j = 0; j < 4; j++) {
      ushort4 o;
      o.x = f2bf_bits(acc[i][j][0]); o.y = f2bf_bits(acc[i][j][1]);
      o.z = f2bf_bits(acc[i][j][2]); o.w = f2bf_bits(acc[i][j][3]);
      *(ushort4*)&Drows[obase + j * 16 + q * 4] = o;
    }
  }
}

// ---------- gather: out[b] = enc[b] + Drows[pos(b,0)] + Drows[pos(b,1)] ----------
__global__ __launch_bounds__(256) void gather_kernel(
    const unsigned short* __restrict__ encb, const unsigned short* __restrict__ Drows,
    const int* __restrict__ pos, float* __restrict__ out) {
  int b = blockIdx.x;
  int t = threadIdx.x;           // cols t*8 .. t*8+7
  int p0 = pos[b * 2], p1 = pos[b * 2 + 1];
  u16x8 e8 = *(const u16x8*)(encb + (size_t)b * D_MOD + t * 8);
  u16x8 d0 = *(const u16x8*)(Drows + (size_t)p0 * D_MOD + t * 8);
  u16x8 d1 = *(const u16x8*)(Drows + (size_t)p1 * D_MOD + t * 8);
  float o[8];
#pragma unroll
  for (int k = 0; k < 8; k++) o[k] = bf2f(e8[k]) + bf2f(d0[k]) + bf2f(d1[k]);
  float4* op = (float4*)(out + (size_t)b * D_MOD + t * 8);
  op[0] = make_float4(o[0], o[1], o[2], o[3]);
  op[1] = make_float4(o[4], o[5], o[6], o[7]);
}

// ---------- launch ----------
extern "C" void kernel_launch(void* const* d_in, const int* in_sizes, int n_in,
                              void* d_out, int out_size, void* d_ws, size_t ws_size,
                              hipStream_t stream) {
  const float* x    = (const float*)d_in[0];
  const float* Wenc = (const float*)d_in[1];
  const float* benc = (const float*)d_in[2];
  const float* Wg   = (const float*)d_in[3];
  const float* U    = (const float*)d_in[4];
  const float* V    = (const float*)d_in[5];
  const float* gamma= (const float*)d_in[6];
  float* out = (float*)d_out;

  char* ws = (char*)d_ws;
  size_t off = 0;
  auto alloc = [&](size_t bytes) { size_t o = off; off = (off + bytes + 255) & ~(size_t)255; return o; };
  unsigned short* xb    = (unsigned short*)(ws + alloc((size_t)B_TOK * D_MOD * 2));
  unsigned short* Wencb = (unsigned short*)(ws + alloc((size_t)D_MOD * D_MOD * 2));
  unsigned short* encb  = (unsigned short*)(ws + alloc((size_t)B_TOK * D_MOD * 2));
  unsigned short* Ub    = (unsigned short*)(ws + alloc((size_t)N_EXP * R_RK * D_MOD * 2));
  unsigned short* Vb    = (unsigned short*)(ws + alloc((size_t)N_EXP * D_MOD * R_RK * 2));
  float*  WgEffF = (float*)(ws + alloc((size_t)N_EXP * D_MOD * 4));
  double* part  = (double*)(ws + alloc((size_t)32 * N_EXP * D_MOD * 8));
  double* biasd = (double*)(ws + alloc(N_EXP * 8));
  int* counts   = (int*)(ws + alloc(64));
  int* cursor   = (int*)(ws + alloc(64));
  int* tile2e   = (int*)(ws + alloc(MAXTILES * 4));
  int* tke      = (int*)(ws + alloc((size_t)B_TOK * 2 * 4));
  float* tkw    = (float*)(ws + alloc((size_t)B_TOK * 2 * 4));
  int* pos      = (int*)(ws + alloc((size_t)B_TOK * 2 * 4));
  int* tok_row  = (int*)(ws + alloc((size_t)MAXROWS * 4));
  float* w_row  = (float*)(ws + alloc((size_t)MAXROWS * 4));
  unsigned short* S = (unsigned short*)(ws + alloc((size_t)MAXROWS * R_RK * 2));
  unsigned short* Drows = (unsigned short*)(ws + alloc((size_t)MAXROWS * D_MOD * 2));
  (void)ws_size; (void)in_sizes; (void)n_in; (void)out_size;

  init_kernel<<<(MAXROWS + 255) / 256, 256, 0, stream>>>(counts, tok_row, w_row);

  int cvt_total = CVT_N0 + CVT_N1 + CVT_N2 + CVT_N3;
  cvt_all<<<(cvt_total + 255) / 256, 256, 0, stream>>>(x, Wenc, U, V, xb, Wencb, Ub, Vb);

  wgeff_partial<<<dim3(8, 32), 256, 0, stream>>>(Wg, Wenc, part);
  wgeff_reduce<<<dim3(8, N_EXP), 256, 0, stream>>>(part, WgEffF);
  bias_kernel<<<N_EXP, 256, 0, stream>>>(benc, Wg, biasd);

  routing_kernel<<<B_TOK / 16, 256, 0, stream>>>(x, WgEffF, biasd, counts, tke, tkw);
  bases_kernel<<<1, 64, 0, stream>>>(counts, cursor, tile2e);
  scatter_kernel<<<(B_TOK + 255) / 256, 256, 0, stream>>>(tke, tkw, gamma, cursor, tok_row, w_row, pos);

  gemm_enc<<<dim3(B_TOK / 128, D_MOD / 128), 256, 0, stream>>>(xb, Wencb, encb);
  gemm_up<<<MAXTILES, 256, 0, stream>>>(encb, Ub, tile2e, tok_row, w_row, S);
  gemm_down<<<dim3(MAXTILES, D_MOD / 128), 256, 0, stream>>>(S, Vb, tile2e, Drows);
  gather_kernel<<<B_TOK, 256, 0, stream>>>(encb, Drows, pos, out);
}

// Round 5
// 866.992 us; speedup vs baseline: 1.0557x; 1.0557x over previous
//
#include <hip/hip_runtime.h>
#include <hip/hip_bf16.h>

#define B_TOK 16384
#define D_MOD 2048
#define N_EXP 16
#define R_RK  128
#define MAXTILES 272              // ceil-aligned (B*2 + 16*127)/128 <= 272
#define MAXROWS (MAXTILES * 128)  // 34816

typedef __bf16 bf16x8 __attribute__((ext_vector_type(8)));
typedef float  f32x4  __attribute__((ext_vector_type(4)));
typedef unsigned short u16x8 __attribute__((ext_vector_type(8)));

// ---------- helpers ----------
__device__ __forceinline__ unsigned short f2bf_bits(float f) {
  unsigned u = __float_as_uint(f);
  u += 0x7fffu + ((u >> 16) & 1u);   // RNE
  return (unsigned short)(u >> 16);
}
__device__ __forceinline__ float bf2f(unsigned short b) {
  return __uint_as_float((unsigned)b << 16);
}

__device__ __forceinline__ void gl2lds16(const void* g, void* l) {
  __builtin_amdgcn_global_load_lds((__attribute__((address_space(1))) void*)(void*)g,
                                   (__attribute__((address_space(3))) void*)l, 16, 0, 0);
}

// ---------- init: counts + pad rows ----------
__global__ void init_kernel(int* counts, int* tok_row, float* w_row) {
  int i = blockIdx.x * 256 + threadIdx.x;
  if (i < N_EXP) counts[i] = 0;
  if (i < MAXROWS) { tok_row[i] = 0; w_row[i] = 0.0f; }
}

// ---------- merged f32->bf16 conversions (x, Wenc, U, V) ----------
#define CVT_N0 (B_TOK * D_MOD / 4)
#define CVT_N1 (D_MOD * D_MOD / 4)
#define CVT_N2 (N_EXP * R_RK * D_MOD / 4)
#define CVT_N3 (N_EXP * D_MOD * R_RK / 4)
__global__ void cvt_all(const float* __restrict__ x, const float* __restrict__ Wenc,
                        const float* __restrict__ U, const float* __restrict__ V,
                        unsigned short* __restrict__ xb, unsigned short* __restrict__ Wencb,
                        unsigned short* __restrict__ Ub, unsigned short* __restrict__ Vb) {
  int i = blockIdx.x * 256 + threadIdx.x;
  const float4* s; ushort4* d; int j;
  if (i < CVT_N0) { s = (const float4*)x; d = (ushort4*)xb; j = i; }
  else if (i < CVT_N0 + CVT_N1) { s = (const float4*)Wenc; d = (ushort4*)Wencb; j = i - CVT_N0; }
  else if (i < CVT_N0 + CVT_N1 + CVT_N2) { s = (const float4*)U; d = (ushort4*)Ub; j = i - CVT_N0 - CVT_N1; }
  else if (i < CVT_N0 + CVT_N1 + CVT_N2 + CVT_N3) { s = (const float4*)V; d = (ushort4*)Vb; j = i - CVT_N0 - CVT_N1 - CVT_N2; }
  else return;
  float4 v = s[j];
  ushort4 o;
  o.x = f2bf_bits(v.x); o.y = f2bf_bits(v.y);
  o.z = f2bf_bits(v.z); o.w = f2bf_bits(v.w);
  d[j] = o;
}

// ---------- fp64 routing pipeline ----------
__global__ void wgeff_partial(const float* __restrict__ Wg, const float* __restrict__ Wenc,
                              double* __restrict__ part) {
  int k = blockIdx.x * 256 + threadIdx.x;
  int dc = blockIdx.y;
  double acc[N_EXP];
#pragma unroll
  for (int m = 0; m < N_EXP; m++) acc[m] = 0.0;
  for (int d = dc * 64; d < dc * 64 + 64; ++d) {
    double we = (double)Wenc[(size_t)d * D_MOD + k];
#pragma unroll
    for (int m = 0; m < N_EXP; m++) acc[m] += (double)Wg[m * D_MOD + d] * we;
  }
#pragma unroll
  for (int m = 0; m < N_EXP; m++) part[((size_t)dc * N_EXP + m) * D_MOD + k] = acc[m];
}

__global__ void wgeff_reduce(const double* __restrict__ part, float* __restrict__ WgEffF) {
  int k = blockIdx.x * 256 + threadIdx.x;
  int m = blockIdx.y;
  double s = 0.0;
#pragma unroll
  for (int dc = 0; dc < 32; dc++) s += part[((size_t)dc * N_EXP + m) * D_MOD + k];
  WgEffF[(size_t)m * D_MOD + k] = (float)s;
}

__global__ void bias_kernel(const float* __restrict__ benc, const float* __restrict__ Wg,
                            double* __restrict__ biasd) {
  int m = blockIdx.x;
  double s = 0.0;
  for (int d = threadIdx.x; d < D_MOD; d += 256)
    s += (double)benc[d] * (double)Wg[m * D_MOD + d];
  __shared__ double red[256];
  red[threadIdx.x] = s;
  __syncthreads();
  for (int st = 128; st; st >>= 1) {
    if (threadIdx.x < st) red[threadIdx.x] += red[threadIdx.x + st];
    __syncthreads();
  }
  if (threadIdx.x == 0) biasd[m] = red[0];
}

// logits (fp64 accum) + top-2 + softmax + counts. (proven fast in R2, unchanged)
__global__ __launch_bounds__(256, 2) void routing_kernel(
    const float* __restrict__ x, const float* __restrict__ WgEffF, const double* __restrict__ biasd,
    int* __restrict__ counts, int* __restrict__ tke, float* __restrict__ tkw) {
  __shared__ float xs[2][16 * 256];
  __shared__ float wgs[2][16 * 256];
  const int tid = threadIdx.x;
  const int wv = tid >> 6, lane = tid & 63;
  const int b0 = blockIdx.x * 16;

  double acc[4][N_EXP];
#pragma unroll
  for (int t = 0; t < 4; t++)
#pragma unroll
    for (int m = 0; m < N_EXP; m++) acc[t][m] = 0.0;

  auto stage = [&](int buf, int ch) {
#pragma unroll
    for (int r = 0; r < 8; r++) {
      int row = wv * 8 + r;
      const float* g;
      float* l;
      if (row < 16) { g = x + (size_t)(b0 + row) * D_MOD + ch * 256; l = &xs[buf][row * 256]; }
      else          { g = WgEffF + (size_t)(row - 16) * D_MOD + ch * 256; l = &wgs[buf][(row - 16) * 256]; }
      gl2lds16(g + (size_t)lane * 4, l);
    }
  };

  stage(0, 0);
  for (int ch = 0; ch < 8; ch++) {
    __syncthreads();
    if (ch < 7) stage((ch + 1) & 1, ch + 1);
    const float* xb = &xs[ch & 1][0];
    const float* wb = &wgs[ch & 1][0];
#pragma unroll
    for (int i = 0; i < 2; i++) {
      int dl = i * 128 + lane * 2;
      float2 xv[4];
#pragma unroll
      for (int t = 0; t < 4; t++) xv[t] = *(const float2*)&xb[(wv * 4 + t) * 256 + dl];
#pragma unroll
      for (int m = 0; m < N_EXP; m++) {
        float2 wv2 = *(const float2*)&wb[m * 256 + dl];
        double w0 = (double)wv2.x, w1 = (double)wv2.y;
#pragma unroll
        for (int t = 0; t < 4; t++) {
          acc[t][m] = fma((double)xv[t].x, w0, acc[t][m]);
          acc[t][m] = fma((double)xv[t].y, w1, acc[t][m]);
        }
      }
    }
  }

#pragma unroll
  for (int t = 0; t < 4; t++)
#pragma unroll
    for (int m = 0; m < N_EXP; m++) {
      double v = acc[t][m];
#pragma unroll
      for (int off = 32; off; off >>= 1) v += __shfl_xor(v, off);
      acc[t][m] = v;
    }

#pragma unroll
  for (int t = 0; t < 4; t++) {
    if (lane == t) {
      int b = b0 + wv * 4 + t;
      double vm[N_EXP];
#pragma unroll
      for (int m = 0; m < N_EXP; m++) vm[m] = acc[t][m] + biasd[m];  // TAU = 1.0
      double v1 = vm[0]; int i1 = 0;
#pragma unroll
      for (int m = 1; m < N_EXP; m++) if (vm[m] > v1) { v1 = vm[m]; i1 = m; }
      double v2 = -1e300; int i2 = 0;
#pragma unroll
      for (int m = 0; m < N_EXP; m++) if (m != i1 && vm[m] > v2) { v2 = vm[m]; i2 = m; }
      double ex = exp(v2 - v1);
      double den = 1.0 + ex;
      float w1 = (float)(1.0 / den), w2 = (float)(ex / den);
      if (!(w1 > 1e-12f)) w1 = 0.0f;
      if (!(w2 > 1e-12f)) w2 = 0.0f;
      tke[b * 2] = i1; tke[b * 2 + 1] = i2;
      tkw[b * 2] = w1; tkw[b * 2 + 1] = w2;
      atomicAdd(&counts[i1], 1);
      atomicAdd(&counts[i2], 1);
    }
  }
}

__global__ void bases_kernel(const int* __restrict__ counts, int* cursor, int* tile2e) {
  if (threadIdx.x == 0) {
    int b = 0;
    for (int e = 0; e < N_EXP; e++) {
      cursor[e] = b;
      int nt = (counts[e] + 127) >> 7;
      for (int t = 0; t < nt; t++) tile2e[b / 128 + t] = e;
      b += nt * 128;
    }
    for (int rt = b / 128; rt < MAXTILES; rt++) tile2e[rt] = -1;
  }
}

__global__ void scatter_kernel(const int* __restrict__ tke, const float* __restrict__ tkw,
                               const float* __restrict__ gamma, int* cursor,
                               int* __restrict__ tok_row, float* __restrict__ w_row,
                               int* __restrict__ pos) {
  int b = blockIdx.x * 256 + threadIdx.x;
  if (b >= B_TOK) return;
#pragma unroll
  for (int s = 0; s < 2; s++) {
    int e = tke[b * 2 + s];
    float w = tkw[b * 2 + s] * gamma[e];
    int p = atomicAdd(&cursor[e], 1);
    tok_row[p] = b; w_row[p] = w;
    pos[b * 2 + s] = p;
  }
}

// ============ GEMM 1: 256x256 tile, BK=64, 8-wave, 8-phase schedule with
// conflict-free XOR swizzle (chunk ^= row&7, pre-swizzled global source +
// swizzled ds_read), counted vmcnt(6) once per K-tile (never 0 in-loop),
// setprio around MFMA clusters, XCD-aware block swizzle.
// Wave grid 2x4; per-wave C = 128 rows x 64 cols, interleaved frag ownership:
//   wave's i-th frag-row = global 2i+wr; j-th frag-col = global 4j+wc.
// Region deadness: A-half0 read only ph0, B-half0 ph0, B-half1 ph1, A-half1 ph2.
// Stage targets: ph0->A1(kt+1)[other buf], ph1->A0(kt+2), ph2->B0(kt+2), ph3->B1(kt+2).
__global__ __launch_bounds__(512, 2) void gemm_enc(
    const unsigned short* __restrict__ A,   // x_bf16 [B, D]
    const unsigned short* __restrict__ Bm,  // Wenc_bf16 [D, D] (rows = out cols)
    unsigned short* __restrict__ encb) {    // [B, D]
  __shared__ unsigned short lA[2][2][128 * 64];  // [buf][half][row*64 + slot*8]: 64 KB
  __shared__ unsigned short lB[2][2][128 * 64];  // 64 KB
  const int tid = threadIdx.x;
  const int wid = tid >> 6, lane = tid & 63;
  const int q = lane >> 4, l16 = lane & 15;
  const int wr = wid >> 2, wc = wid & 3;

  // XCD swizzle: 512 blocks, 8 XCDs -> each XCD gets 8 consecutive tm (all tn)
  const int flat = blockIdx.x;
  const int swz = (flat & 7) * 64 + (flat >> 3);
  const int tm = swz >> 3, tn = swz & 7;

  const unsigned short* Ag = A + (size_t)(tm * 256) * D_MOD;
  const unsigned short* Bg = Bm + (size_t)(tn * 256) * D_MOD;

  const int srow = wid * 8 + (lane >> 3);  // staging row within half (call c adds c*64)
  const int schunk = lane & 7;

  // stage one 128x64 half-tile: 2 block-wide gl2lds calls (1 instr/wave each).
  // LDS dest linear; global source chunk pre-swizzled: slot s holds chunk s^(row&7).
  auto stage = [&](unsigned short* lbase, const unsigned short* gbase) {
#pragma unroll
    for (int c = 0; c < 2; ++c) {
      int row = c * 64 + srow;
      gl2lds16(gbase + (size_t)row * D_MOD + (size_t)((schunk ^ (row & 7)) * 8),
               lbase + c * 4096 + wid * 512);  // wave-uniform base; HW adds lane*16B
    }
  };
  // fragment read with matching swizzle: logical chunk kh*4+q at LDS slot ^ (l16&7)
  auto ldfrag = [&](const unsigned short* base, int rowhi, int kh) -> bf16x8 {
    int row = rowhi * 16 + l16;
    int slot = ((kh << 2) + q) ^ (l16 & 7);
    return *(const bf16x8*)&base[row * 64 + slot * 8];
  };

  f32x4 acc[8][4] = {};
  bf16x8 af[4][2], bfr[4][2];

  // Prologue: 7 half-tiles (A0/B0/B1/A1 of kt0; A0/B0/B1 of kt1), vmcnt(6) -> first 4 landed.
  stage(&lA[0][0][0], Ag);
  stage(&lB[0][0][0], Bg);
  stage(&lB[0][1][0], Bg + (size_t)128 * D_MOD);
  stage(&lA[0][1][0], Ag + (size_t)128 * D_MOD);
  stage(&lA[1][0][0], Ag + 64);
  stage(&lB[1][0][0], Bg + 64);
  stage(&lB[1][1][0], Bg + (size_t)128 * D_MOD + 64);
  asm volatile("s_waitcnt vmcnt(6)" ::: "memory");
  __builtin_amdgcn_s_barrier();
  asm volatile("" ::: "memory");

#pragma unroll 1
  for (int kt = 0; kt < 32; ++kt) {
    const int b = kt & 1;
    const unsigned short* A0 = &lA[b][0][0];
    const unsigned short* A1 = &lA[b][1][0];
    const unsigned short* B0 = &lB[b][0][0];
    const unsigned short* B1 = &lB[b][1][0];
    // ---- phase 0: read A i0-3 (A-half0) + B j0-1 (B-half0); stage A1(kt+1)
#pragma unroll
    for (int i = 0; i < 4; ++i) {
      af[i][0] = ldfrag(A0, 2 * i + wr, 0);
      af[i][1] = ldfrag(A0, 2 * i + wr, 1);
    }
#pragma unroll
    for (int j = 0; j < 2; ++j) {
      bfr[j][0] = ldfrag(B0, 4 * j + wc, 0);
      bfr[j][1] = ldfrag(B0, 4 * j + wc, 1);
    }
    if (kt + 1 < 32) stage(&lA[b ^ 1][1][0], Ag + (size_t)128 * D_MOD + (size_t)(kt + 1) * 64);
    asm volatile("" ::: "memory");
    __builtin_amdgcn_s_barrier();
    __builtin_amdgcn_s_setprio(1);
#pragma unroll
    for (int i = 0; i < 4; ++i)
#pragma unroll
      for (int j = 0; j < 2; ++j) {
        acc[i][j] = __builtin_amdgcn_mfma_f32_16x16x32_bf16(bfr[j][0], af[i][0], acc[i][j], 0, 0, 0);
        acc[i][j] = __builtin_amdgcn_mfma_f32_16x16x32_bf16(bfr[j][1], af[i][1], acc[i][j], 0, 0, 0);
      }
    __builtin_amdgcn_s_setprio(0);
    asm volatile("" ::: "memory");
    __builtin_amdgcn_s_barrier();
    asm volatile("" ::: "memory");
    // ---- phase 1: read B j2-3 (B-half1); stage A0(kt+2) [A-half0 dead after ph0]
#pragma unroll
    for (int j = 2; j < 4; ++j) {
      bfr[j][0] = ldfrag(B1, 4 * j + wc - 8, 0);
      bfr[j][1] = ldfrag(B1, 4 * j + wc - 8, 1);
    }
    if (kt + 2 < 32) stage(&lA[b][0][0], Ag + (size_t)(kt + 2) * 64);
    asm volatile("" ::: "memory");
    __builtin_amdgcn_s_barrier();
    __builtin_amdgcn_s_setprio(1);
#pragma unroll
    for (int i = 0; i < 4; ++i)
#pragma unroll
      for (int j = 2; j < 4; ++j) {
        acc[i][j] = __builtin_amdgcn_mfma_f32_16x16x32_bf16(bfr[j][0], af[i][0], acc[i][j], 0, 0, 0);
        acc[i][j] = __builtin_amdgcn_mfma_f32_16x16x32_bf16(bfr[j][1], af[i][1], acc[i][j], 0, 0, 0);
      }
    __builtin_amdgcn_s_setprio(0);
    asm volatile("" ::: "memory");
    __builtin_amdgcn_s_barrier();
    asm volatile("" ::: "memory");
    // ---- phase 2: read A i4-7 (A-half1); stage B0(kt+2) [B-half0 dead after ph0]
#pragma unroll
    for (int i = 0; i < 4; ++i) {
      af[i][0] = ldfrag(A1, 2 * i + wr, 0);
      af[i][1] = ldfrag(A1, 2 * i + wr, 1);
    }
    if (kt + 2 < 32) stage(&lB[b][0][0], Bg + (size_t)(kt + 2) * 64);
    asm volatile("" ::: "memory");
    __builtin_amdgcn_s_barrier();
    __builtin_amdgcn_s_setprio(1);
#pragma unroll
    for (int i = 0; i < 4; ++i)
#pragma unroll
      for (int j = 0; j < 2; ++j) {
        acc[i + 4][j] = __builtin_amdgcn_mfma_f32_16x16x32_bf16(bfr[j][0], af[i][0], acc[i + 4][j], 0, 0, 0);
        acc[i + 4][j] = __builtin_amdgcn_mfma_f32_16x16x32_bf16(bfr[j][1], af[i][1], acc[i + 4][j], 0, 0, 0);
      }
    __builtin_amdgcn_s_setprio(0);
    asm volatile("" ::: "memory");
    __builtin_amdgcn_s_barrier();
    asm volatile("" ::: "memory");
    // ---- phase 3: reg-only MFMA; stage B1(kt+2) [B-half1 dead after ph1]; counted vmcnt
    if (kt + 2 < 32) stage(&lB[b][1][0], Bg + (size_t)128 * D_MOD + (size_t)(kt + 2) * 64);
    asm volatile("" ::: "memory");
    __builtin_amdgcn_s_barrier();
    __builtin_amdgcn_s_setprio(1);
#pragma unroll
    for (int i = 0; i < 4; ++i)
#pragma unroll
      for (int j = 2; j < 4; ++j) {
        acc[i + 4][j] = __builtin_amdgcn_mfma_f32_16x16x32_bf16(bfr[j][0], af[i][0], acc[i + 4][j], 0, 0, 0);
        acc[i + 4][j] = __builtin_amdgcn_mfma_f32_16x16x32_bf16(bfr[j][1], af[i][1], acc[i + 4][j], 0, 0, 0);
      }
    __builtin_amdgcn_s_setprio(0);
    if (kt == 30) asm volatile("s_waitcnt vmcnt(0)" ::: "memory");
    else          asm volatile("s_waitcnt vmcnt(6)" ::: "memory");
    __builtin_amdgcn_s_barrier();
    asm volatile("" ::: "memory");
  }

  // epilogue: swapped-operand C layout -> row = l16, cols = q*4+reg (ushort4 stores)
#pragma unroll
  for (int i = 0; i < 8; ++i) {
    int row = tm * 256 + (2 * i + wr) * 16 + l16;
#pragma unroll
    for (int j = 0; j < 4; ++j) {
      int col = tn * 256 + (4 * j + wc) * 16 + q * 4;
      ushort4 o;
      o.x = f2bf_bits(acc[i][j][0]); o.y = f2bf_bits(acc[i][j][1]);
      o.z = f2bf_bits(acc[i][j][2]); o.w = f2bf_bits(acc[i][j][3]);
      *(ushort4*)&encb[(size_t)row * D_MOD + col] = o;
    }
  }
}

// ---------- GEMM 2: S = silu(enc_gathered @ U[e]^T) * (w*gamma) ----------
// R2-proven 2-barrier loop + R3-verified swapped-operand ushort4 epilogue.
__global__ __launch_bounds__(256) void gemm_up(
    const unsigned short* __restrict__ encb,
    const unsigned short* __restrict__ Ub,
    const int* __restrict__ tile2e, const int* __restrict__ tok_row,
    const float* __restrict__ w_row,
    unsigned short* __restrict__ S) {
  const int rt = blockIdx.x;
  const int e = tile2e[rt];
  if (e < 0) return;
  __shared__ unsigned short lA[128 * 32], lB[128 * 32];
  const int tid = threadIdx.x;
  const int wv = tid >> 6, lane = tid & 63;
  const int q = lane >> 4, l16 = lane & 15;

  const int srow = wv * 16 + (lane >> 2);
  const int scol = (lane & 3) * 8;
  const int tok0 = tok_row[rt * 128 + srow];
  const int tok1 = tok_row[rt * 128 + srow + 64];
  const unsigned short* ga0 = encb + (size_t)tok0 * D_MOD + scol;
  const unsigned short* ga1 = encb + (size_t)tok1 * D_MOD + scol;
  const unsigned short* gbase = Ub + (size_t)e * R_RK * D_MOD;
  const unsigned short* gb0 = gbase + (size_t)srow * D_MOD + scol;
  const unsigned short* gb1 = gb0 + (size_t)64 * D_MOD;
  unsigned short* la0 = &lA[(wv * 16) * 32];
  unsigned short* la1 = &lA[(wv * 16 + 64) * 32];
  unsigned short* lb0 = &lB[(wv * 16) * 32];
  unsigned short* lb1 = &lB[(wv * 16 + 64) * 32];

  const int wm = (wv & 1) * 64, wn = (wv >> 1) * 64;
  f32x4 acc[4][4] = {};

  for (int k0 = 0; k0 < D_MOD; k0 += 32) {
    gl2lds16(ga0 + k0, la0);
    gl2lds16(ga1 + k0, la1);
    gl2lds16(gb0 + k0, lb0);
    gl2lds16(gb1 + k0, lb1);
    __syncthreads();
    bf16x8 af[4], bf[4];
#pragma unroll
    for (int i = 0; i < 4; i++) af[i] = *(const bf16x8*)&lA[(wm + i * 16 + l16) * 32 + q * 8];
#pragma unroll
    for (int j = 0; j < 4; j++) bf[j] = *(const bf16x8*)&lB[(wn + j * 16 + l16) * 32 + q * 8];
#pragma unroll
    for (int i = 0; i < 4; i++)
#pragma unroll
      for (int j = 0; j < 4; j++)
        acc[i][j] = __builtin_amdgcn_mfma_f32_16x16x32_bf16(bf[j], af[i], acc[i][j], 0, 0, 0);
    __syncthreads();
  }
#pragma unroll
  for (int i = 0; i < 4; i++) {
    int prow = rt * 128 + wm + i * 16 + l16;
    float wr = w_row[prow];
#pragma unroll
    for (int j = 0; j < 4; j++) {
      int col = wn + j * 16 + q * 4;
      ushort4 o;
      float v0 = acc[i][j][0], v1 = acc[i][j][1], v2 = acc[i][j][2], v3 = acc[i][j][3];
      o.x = f2bf_bits((v0 / (1.0f + __expf(-v0))) * wr);
      o.y = f2bf_bits((v1 / (1.0f + __expf(-v1))) * wr);
      o.z = f2bf_bits((v2 / (1.0f + __expf(-v2))) * wr);
      o.w = f2bf_bits((v3 / (1.0f + __expf(-v3))) * wr);
      *(ushort4*)&S[(size_t)prow * R_RK + col] = o;
    }
  }
}

// ---------- GEMM 3: Drows = S @ V[e]^T ----------
__global__ __launch_bounds__(256) void gemm_down(
    const unsigned short* __restrict__ S,
    const unsigned short* __restrict__ Vb,
    const int* __restrict__ tile2e,
    unsigned short* __restrict__ Drows) {
  const int rt = blockIdx.x, ct = blockIdx.y;
  const int e = tile2e[rt];
  if (e < 0) return;
  __shared__ unsigned short lA[128 * 32], lB[128 * 32];
  const int tid = threadIdx.x;
  const int wv = tid >> 6, lane = tid & 63;
  const int q = lane >> 4, l16 = lane & 15;

  const int srow = wv * 16 + (lane >> 2);
  const int scol = (lane & 3) * 8;
  const unsigned short* ga0 = S + (size_t)(rt * 128 + srow) * R_RK + scol;
  const unsigned short* ga1 = ga0 + (size_t)64 * R_RK;
  const unsigned short* gb0 = Vb + ((size_t)e * D_MOD + ct * 128 + srow) * R_RK + scol;
  const unsigned short* gb1 = gb0 + (size_t)64 * R_RK;
  unsigned short* la0 = &lA[(wv * 16) * 32];
  unsigned short* la1 = &lA[(wv * 16 + 64) * 32];
  unsigned short* lb0 = &lB[(wv * 16) * 32];
  unsigned short* lb1 = &lB[(wv * 16 + 64) * 32];

  const int wm = (wv & 1) * 64, wn = (wv >> 1) * 64;
  f32x4 acc[4][4] = {};

  for (int k0 = 0; k0 < R_RK; k0 += 32) {
    gl2lds16(ga0 + k0, la0);
    gl2lds16(ga1 + k0, la1);
    gl2lds16(gb0 + k0, lb0);
    gl2lds16(gb1 + k0, lb1);
    __syncthreads();
    bf16x8 af[4], bf[4];
#pragma unroll
    for (int i = 0; i < 4; i++) af[i] = *(const bf16x8*)&lA[(wm + i * 16 + l16) * 32 + q * 8];
#pragma unroll
    for (int j = 0; j < 4; j++) bf[j] = *(const bf16x8*)&lB[(wn + j * 16 + l16) * 32 + q * 8];
#pragma unroll
    for (int i = 0; i < 4; i++)
#pragma unroll
      for (int j = 0; j < 4; j++)
        acc[i][j] = __builtin_amdgcn_mfma_f32_16x16x32_bf16(bf[j], af[i], acc[i][j], 0, 0, 0);
    __syncthreads();
  }
#pragma unroll
  for (int i = 0; i < 4; i++) {
    int prow = rt * 128 + wm + i * 16 + l16;
    size_t obase = (size_t)prow * D_MOD + ct * 128 + wn;
#pragma unroll
    for (int j = 0; j < 4; j++) {
      ushort4 o;
      o.x = f2bf_bits(acc[i][j][0]); o.y = f2bf_bits(acc[i][j][1]);
      o.z = f2bf_bits(acc[i][j][2]); o.w = f2bf_bits(acc[i][j][3]);
      *(ushort4*)&Drows[obase + j * 16 + q * 4] = o;
    }
  }
}

// ---------- gather: out[b] = enc[b] + Drows[pos(b,0)] + Drows[pos(b,1)] ----------
__global__ __launch_bounds__(256) void gather_kernel(
    const unsigned short* __restrict__ encb, const unsigned short* __restrict__ Drows,
    const int* __restrict__ pos, float* __restrict__ out) {
  int b = blockIdx.x;
  int t = threadIdx.x;
  int p0 = pos[b * 2], p1 = pos[b * 2 + 1];
  u16x8 e8 = *(const u16x8*)(encb + (size_t)b * D_MOD + t * 8);
  u16x8 d0 = *(const u16x8*)(Drows + (size_t)p0 * D_MOD + t * 8);
  u16x8 d1 = *(const u16x8*)(Drows + (size_t)p1 * D_MOD + t * 8);
  float o[8];
#pragma unroll
  for (int k = 0; k < 8; k++) o[k] = bf2f(e8[k]) + bf2f(d0[k]) + bf2f(d1[k]);
  float4* op = (float4*)(out + (size_t)b * D_MOD + t * 8);
  op[0] = make_float4(o[0], o[1], o[2], o[3]);
  op[1] = make_float4(o[4], o[5], o[6], o[7]);
}

// ---------- launch ----------
extern "C" void kernel_launch(void* const* d_in, const int* in_sizes, int n_in,
                              void* d_out, int out_size, void* d_ws, size_t ws_size,
                              hipStream_t stream) {
  const float* x    = (const float*)d_in[0];
  const float* Wenc = (const float*)d_in[1];
  const float* benc = (const float*)d_in[2];
  const float* Wg   = (const float*)d_in[3];
  const float* U    = (const float*)d_in[4];
  const float* V    = (const float*)d_in[5];
  const float* gamma= (const float*)d_in[6];
  float* out = (float*)d_out;

  char* ws = (char*)d_ws;
  size_t off = 0;
  auto alloc = [&](size_t bytes) { size_t o = off; off = (off + bytes + 255) & ~(size_t)255; return o; };
  unsigned short* xb    = (unsigned short*)(ws + alloc((size_t)B_TOK * D_MOD * 2));
  unsigned short* Wencb = (unsigned short*)(ws + alloc((size_t)D_MOD * D_MOD * 2));
  unsigned short* encb  = (unsigned short*)(ws + alloc((size_t)B_TOK * D_MOD * 2));
  unsigned short* Ub    = (unsigned short*)(ws + alloc((size_t)N_EXP * R_RK * D_MOD * 2));
  unsigned short* Vb    = (unsigned short*)(ws + alloc((size_t)N_EXP * D_MOD * R_RK * 2));
  float*  WgEffF = (float*)(ws + alloc((size_t)N_EXP * D_MOD * 4));
  double* part  = (double*)(ws + alloc((size_t)32 * N_EXP * D_MOD * 8));
  double* biasd = (double*)(ws + alloc(N_EXP * 8));
  int* counts   = (int*)(ws + alloc(64));
  int* cursor   = (int*)(ws + alloc(64));
  int* tile2e   = (int*)(ws + alloc(MAXTILES * 4));
  int* tke      = (int*)(ws + alloc((size_t)B_TOK * 2 * 4));
  float* tkw    = (float*)(ws + alloc((size_t)B_TOK * 2 * 4));
  int* pos      = (int*)(ws + alloc((size_t)B_TOK * 2 * 4));
  int* tok_row  = (int*)(ws + alloc((size_t)MAXROWS * 4));
  float* w_row  = (float*)(ws + alloc((size_t)MAXROWS * 4));
  unsigned short* S = (unsigned short*)(ws + alloc((size_t)MAXROWS * R_RK * 2));
  unsigned short* Drows = (unsigned short*)(ws + alloc((size_t)MAXROWS * D_MOD * 2));
  (void)ws_size; (void)in_sizes; (void)n_in; (void)out_size;

  init_kernel<<<(MAXROWS + 255) / 256, 256, 0, stream>>>(counts, tok_row, w_row);

  int cvt_total = CVT_N0 + CVT_N1 + CVT_N2 + CVT_N3;
  cvt_all<<<(cvt_total + 255) / 256, 256, 0, stream>>>(x, Wenc, U, V, xb, Wencb, Ub, Vb);

  wgeff_partial<<<dim3(8, 32), 256, 0, stream>>>(Wg, Wenc, part);
  wgeff_reduce<<<dim3(8, N_EXP), 256, 0, stream>>>(part, WgEffF);
  bias_kernel<<<N_EXP, 256, 0, stream>>>(benc, Wg, biasd);

  routing_kernel<<<B_TOK / 16, 256, 0, stream>>>(x, WgEffF, biasd, counts, tke, tkw);
  bases_kernel<<<1, 64, 0, stream>>>(counts, cursor, tile2e);
  scatter_kernel<<<(B_TOK + 255) / 256, 256, 0, stream>>>(tke, tkw, gamma, cursor, tok_row, w_row, pos);

  gemm_enc<<<(B_TOK / 256) * (D_MOD / 256), 512, 0, stream>>>(xb, Wencb, encb);
  gemm_up<<<MAXTILES, 256, 0, stream>>>(encb, Ub, tile2e, tok_row, w_row, S);
  gemm_down<<<dim3(MAXTILES, D_MOD / 128), 256, 0, stream>>>(S, Vb, tile2e, Drows);
  gather_kernel<<<B_TOK, 256, 0, stream>>>(encb, Drows, pos, out);
}

// Round 7
// 672.918 us; speedup vs baseline: 1.3602x; 1.2884x over previous
//
#include <hip/hip_runtime.h>
#include <hip/hip_bf16.h>

#define B_TOK 16384
#define D_MOD 2048
#define N_EXP 16
#define R_RK  128
#define MAXTILES 272              // ceil-aligned (B*2 + 16*127)/128 <= 272
#define MAXROWS (MAXTILES * 128)  // 34816

typedef __bf16 bf16x8 __attribute__((ext_vector_type(8)));
typedef float  f32x4  __attribute__((ext_vector_type(4)));
typedef unsigned short u16x8 __attribute__((ext_vector_type(8)));

// ---------- helpers ----------
__device__ __forceinline__ unsigned short f2bf_bits(float f) {
  unsigned u = __float_as_uint(f);
  u += 0x7fffu + ((u >> 16) & 1u);   // RNE
  return (unsigned short)(u >> 16);
}
__device__ __forceinline__ float bf2f(unsigned short b) {
  return __uint_as_float((unsigned)b << 16);
}

__device__ __forceinline__ void gl2lds16(const void* g, void* l) {
  __builtin_amdgcn_global_load_lds((__attribute__((address_space(1))) void*)(void*)g,
                                   (__attribute__((address_space(3))) void*)l, 16, 0, 0);
}

// ---------- init: counts + pad rows ----------
__global__ void init_kernel(int* counts, int* tok_row, float* w_row) {
  int i = blockIdx.x * 256 + threadIdx.x;
  if (i < N_EXP) counts[i] = 0;
  if (i < MAXROWS) { tok_row[i] = 0; w_row[i] = 0.0f; }
}

// ---------- merged f32->bf16 conversions (Wenc, U, V; x fused into routing) ----------
#define CVT_N1 (D_MOD * D_MOD / 4)          // 1048576 float4s of Wenc
#define CVT_N2 (N_EXP * R_RK * D_MOD / 4)   // 1048576 U
#define CVT_N3 (N_EXP * D_MOD * R_RK / 4)   // 1048576 V
__global__ void cvt_all(const float* __restrict__ Wenc,
                        const float* __restrict__ U, const float* __restrict__ V,
                        unsigned short* __restrict__ Wencb,
                        unsigned short* __restrict__ Ub, unsigned short* __restrict__ Vb) {
  int i = blockIdx.x * 256 + threadIdx.x;
  const float4* s; ushort4* d; int j;
  if (i < CVT_N1) { s = (const float4*)Wenc; d = (ushort4*)Wencb; j = i; }
  else if (i < CVT_N1 + CVT_N2) { s = (const float4*)U; d = (ushort4*)Ub; j = i - CVT_N1; }
  else if (i < CVT_N1 + CVT_N2 + CVT_N3) { s = (const float4*)V; d = (ushort4*)Vb; j = i - CVT_N1 - CVT_N2; }
  else return;
  float4 v = s[j];
  ushort4 o;
  o.x = f2bf_bits(v.x); o.y = f2bf_bits(v.y);
  o.z = f2bf_bits(v.z); o.w = f2bf_bits(v.w);
  d[j] = o;
}

// ---------- fp64 routing pipeline ----------
__global__ void wgeff_partial(const float* __restrict__ Wg, const float* __restrict__ Wenc,
                              double* __restrict__ part) {
  int k = blockIdx.x * 256 + threadIdx.x;
  int dc = blockIdx.y;
  double acc[N_EXP];
#pragma unroll
  for (int m = 0; m < N_EXP; m++) acc[m] = 0.0;
  for (int d = dc * 64; d < dc * 64 + 64; ++d) {
    double we = (double)Wenc[(size_t)d * D_MOD + k];
#pragma unroll
    for (int m = 0; m < N_EXP; m++) acc[m] += (double)Wg[m * D_MOD + d] * we;
  }
#pragma unroll
  for (int m = 0; m < N_EXP; m++) part[((size_t)dc * N_EXP + m) * D_MOD + k] = acc[m];
}

__global__ void wgeff_reduce(const double* __restrict__ part, float* __restrict__ WgEffF) {
  int k = blockIdx.x * 256 + threadIdx.x;
  int m = blockIdx.y;
  double s = 0.0;
#pragma unroll
  for (int dc = 0; dc < 32; dc++) s += part[((size_t)dc * N_EXP + m) * D_MOD + k];
  WgEffF[(size_t)m * D_MOD + k] = (float)s;
}

__global__ void bias_kernel(const float* __restrict__ benc, const float* __restrict__ Wg,
                            double* __restrict__ biasd) {
  int m = blockIdx.x;
  double s = 0.0;
  for (int d = threadIdx.x; d < D_MOD; d += 256)
    s += (double)benc[d] * (double)Wg[m * D_MOD + d];
  __shared__ double red[256];
  red[threadIdx.x] = s;
  __syncthreads();
  for (int st = 128; st; st >>= 1) {
    if (threadIdx.x < st) red[threadIdx.x] += red[threadIdx.x + st];
    __syncthreads();
  }
  if (threadIdx.x == 0) biasd[m] = red[0];
}

// routing v3: barrier-free fp64 logits + top-2 + softmax; fused x->bf16 cvt.
// WgEff (16x2048 f32 = 128 KB) staged in LDS ONCE (single barrier); then each
// wave independent: 2 tokens/wave, x read global->reg (coalesced float4),
// W from LDS (conflict-free b128). No atomics (counts via hist_kernel).
// acc = 2x16 fp64 = 64 VGPR; launch_bounds(1024,4) -> <=128 VGPR, 1 block/CU.
__global__ __launch_bounds__(1024, 4) void routing_kernel(
    const float* __restrict__ x, const float* __restrict__ WgEffF, const double* __restrict__ biasd,
    int* __restrict__ tke, float* __restrict__ tkw, unsigned short* __restrict__ xb) {
  __shared__ float wlds[N_EXP * D_MOD];  // 128 KB
  const int tid = threadIdx.x;
  const int wid = tid >> 6, lane = tid & 63;
  const int b0 = blockIdx.x * 32;        // grid = 512

  // stage all of WgEff: 128 chunks x 1KB; 8 chunks per wave. One barrier total.
#pragma unroll
  for (int r = 0; r < 8; ++r) {
    int ch = wid * 8 + r;                // 0..127
    int row = ch >> 3, off = (ch & 7) * 256;
    gl2lds16(WgEffF + (size_t)row * D_MOD + off + (size_t)lane * 4, wlds + ch * 256);
  }
  __syncthreads();

  const float* xr0 = x + (size_t)(b0 + wid * 2) * D_MOD;
  const float* xr1 = xr0 + D_MOD;
  unsigned short* xb0 = xb + (size_t)(b0 + wid * 2) * D_MOD;
  unsigned short* xb1 = xb0 + D_MOD;

  double acc0[N_EXP], acc1[N_EXP];
#pragma unroll
  for (int m = 0; m < N_EXP; m++) { acc0[m] = 0.0; acc1[m] = 0.0; }

#pragma unroll 2
  for (int c = 0; c < 8; ++c) {
    int dbase = c * 256 + lane * 4;
    float4 xv0 = *(const float4*)&xr0[dbase];
    float4 xv1 = *(const float4*)&xr1[dbase];
    // fused bf16 conversion of x (replaces cvt_all's x pass)
    ushort4 o0, o1;
    o0.x = f2bf_bits(xv0.x); o0.y = f2bf_bits(xv0.y); o0.z = f2bf_bits(xv0.z); o0.w = f2bf_bits(xv0.w);
    o1.x = f2bf_bits(xv1.x); o1.y = f2bf_bits(xv1.y); o1.z = f2bf_bits(xv1.z); o1.w = f2bf_bits(xv1.w);
    *(ushort4*)&xb0[dbase] = o0;
    *(ushort4*)&xb1[dbase] = o1;
    double x00 = (double)xv0.x, x01 = (double)xv0.y, x02 = (double)xv0.z, x03 = (double)xv0.w;
    double x10 = (double)xv1.x, x11 = (double)xv1.y, x12 = (double)xv1.z, x13 = (double)xv1.w;
#pragma unroll
    for (int m = 0; m < N_EXP; m++) {
      float4 wv = *(const float4*)&wlds[m * D_MOD + dbase];
      double w0 = (double)wv.x, w1 = (double)wv.y, w2 = (double)wv.z, w3 = (double)wv.w;
      acc0[m] = fma(x00, w0, acc0[m]); acc0[m] = fma(x01, w1, acc0[m]);
      acc0[m] = fma(x02, w2, acc0[m]); acc0[m] = fma(x03, w3, acc0[m]);
      acc1[m] = fma(x10, w0, acc1[m]); acc1[m] = fma(x11, w1, acc1[m]);
      acc1[m] = fma(x12, w2, acc1[m]); acc1[m] = fma(x13, w3, acc1[m]);
    }
  }

  // wave butterfly reduce (all lanes end with full sums)
#pragma unroll
  for (int m = 0; m < N_EXP; m++) {
    double v0 = acc0[m], v1 = acc1[m];
#pragma unroll
    for (int off = 32; off; off >>= 1) { v0 += __shfl_xor(v0, off); v1 += __shfl_xor(v1, off); }
    acc0[m] = v0; acc1[m] = v1;
  }

  if (lane < 2) {
    int b = b0 + wid * 2 + lane;
    double vm[N_EXP];
#pragma unroll
    for (int m = 0; m < N_EXP; m++) vm[m] = (lane ? acc1[m] : acc0[m]) + biasd[m];  // TAU = 1.0
    double v1 = vm[0]; int i1 = 0;
#pragma unroll
    for (int m = 1; m < N_EXP; m++) if (vm[m] > v1) { v1 = vm[m]; i1 = m; }
    double v2 = -1e300; int i2 = 0;
#pragma unroll
    for (int m = 0; m < N_EXP; m++) if (m != i1 && vm[m] > v2) { v2 = vm[m]; i2 = m; }
    double ex = exp(v2 - v1);
    double den = 1.0 + ex;
    float w1 = (float)(1.0 / den), w2 = (float)(ex / den);
    if (!(w1 > 1e-12f)) w1 = 0.0f;
    if (!(w2 > 1e-12f)) w2 = 0.0f;
    tke[b * 2] = i1; tke[b * 2 + 1] = i2;
    tkw[b * 2] = w1; tkw[b * 2 + 1] = w2;
  }
}

// counts from tke via LDS histogram: 512 global atomics total (was 32768 in routing)
__global__ void hist_kernel(const int* __restrict__ tke, int* __restrict__ counts) {
  __shared__ int h[N_EXP];
  if (threadIdx.x < N_EXP) h[threadIdx.x] = 0;
  __syncthreads();
  int i = blockIdx.x * 1024 + threadIdx.x;   // grid = 32
  if (i < B_TOK * 2) atomicAdd(&h[tke[i]], 1);
  __syncthreads();
  if (threadIdx.x < N_EXP) atomicAdd(&counts[threadIdx.x], h[threadIdx.x]);
}

__global__ void bases_kernel(const int* __restrict__ counts, int* cursor, int* tile2e) {
  if (threadIdx.x == 0) {
    int b = 0;
    for (int e = 0; e < N_EXP; e++) {
      cursor[e] = b;
      int nt = (counts[e] + 127) >> 7;
      for (int t = 0; t < nt; t++) tile2e[b / 128 + t] = e;
      b += nt * 128;
    }
    for (int rt = b / 128; rt < MAXTILES; rt++) tile2e[rt] = -1;
  }
}

// scatter with per-block LDS aggregation: 16 global atomics/block (was 512)
__global__ void scatter_kernel(const int* __restrict__ tke, const float* __restrict__ tkw,
                               const float* __restrict__ gamma, int* cursor,
                               int* __restrict__ tok_row, float* __restrict__ w_row,
                               int* __restrict__ pos) {
  __shared__ int lh[N_EXP];
  __shared__ int lbase[N_EXP];
  const int t = threadIdx.x;
  if (t < N_EXP) lh[t] = 0;
  __syncthreads();
  const int b = blockIdx.x * 256 + t;        // grid = 64, exact
  int e0 = tke[b * 2], e1 = tke[b * 2 + 1];
  int r0 = atomicAdd(&lh[e0], 1);
  int r1 = atomicAdd(&lh[e1], 1);
  __syncthreads();
  if (t < N_EXP) lbase[t] = atomicAdd(&cursor[t], lh[t]);
  __syncthreads();
  int p0 = lbase[e0] + r0;
  int p1 = lbase[e1] + r1;
  float w0 = tkw[b * 2] * gamma[e0];
  float w1 = tkw[b * 2 + 1] * gamma[e1];
  tok_row[p0] = b; w_row[p0] = w0; pos[b * 2] = p0;
  tok_row[p1] = b; w_row[p1] = w1; pos[b * 2 + 1] = p1;
}

// ============ GEMM 1: 256x256 tile, BK=64, 8-wave, 8-phase schedule (R5-proven) ============
__global__ __launch_bounds__(512, 2) void gemm_enc(
    const unsigned short* __restrict__ A,   // x_bf16 [B, D]
    const unsigned short* __restrict__ Bm,  // Wenc_bf16 [D, D] (rows = out cols)
    unsigned short* __restrict__ encb) {    // [B, D]
  __shared__ unsigned short lA[2][2][128 * 64];  // [buf][half][row*64 + slot*8]: 64 KB
  __shared__ unsigned short lB[2][2][128 * 64];  // 64 KB
  const int tid = threadIdx.x;
  const int wid = tid >> 6, lane = tid & 63;
  const int q = lane >> 4, l16 = lane & 15;
  const int wr = wid >> 2, wc = wid & 3;

  const int flat = blockIdx.x;
  const int swz = (flat & 7) * 64 + (flat >> 3);
  const int tm = swz >> 3, tn = swz & 7;

  const unsigned short* Ag = A + (size_t)(tm * 256) * D_MOD;
  const unsigned short* Bg = Bm + (size_t)(tn * 256) * D_MOD;

  const int srow = wid * 8 + (lane >> 3);
  const int schunk = lane & 7;

  auto stage = [&](unsigned short* lbase, const unsigned short* gbase) {
#pragma unroll
    for (int c = 0; c < 2; ++c) {
      int row = c * 64 + srow;
      gl2lds16(gbase + (size_t)row * D_MOD + (size_t)((schunk ^ (row & 7)) * 8),
               lbase + c * 4096 + wid * 512);
    }
  };
  auto ldfrag = [&](const unsigned short* base, int rowhi, int kh) -> bf16x8 {
    int row = rowhi * 16 + l16;
    int slot = ((kh << 2) + q) ^ (l16 & 7);
    return *(const bf16x8*)&base[row * 64 + slot * 8];
  };

  f32x4 acc[8][4] = {};
  bf16x8 af[4][2], bfr[4][2];

  stage(&lA[0][0][0], Ag);
  stage(&lB[0][0][0], Bg);
  stage(&lB[0][1][0], Bg + (size_t)128 * D_MOD);
  stage(&lA[0][1][0], Ag + (size_t)128 * D_MOD);
  stage(&lA[1][0][0], Ag + 64);
  stage(&lB[1][0][0], Bg + 64);
  stage(&lB[1][1][0], Bg + (size_t)128 * D_MOD + 64);
  asm volatile("s_waitcnt vmcnt(6)" ::: "memory");
  __builtin_amdgcn_s_barrier();
  asm volatile("" ::: "memory");

#pragma unroll 1
  for (int kt = 0; kt < 32; ++kt) {
    const int b = kt & 1;
    const unsigned short* A0 = &lA[b][0][0];
    const unsigned short* A1 = &lA[b][1][0];
    const unsigned short* B0 = &lB[b][0][0];
    const unsigned short* B1 = &lB[b][1][0];
    // ---- phase 0
#pragma unroll
    for (int i = 0; i < 4; ++i) {
      af[i][0] = ldfrag(A0, 2 * i + wr, 0);
      af[i][1] = ldfrag(A0, 2 * i + wr, 1);
    }
#pragma unroll
    for (int j = 0; j < 2; ++j) {
      bfr[j][0] = ldfrag(B0, 4 * j + wc, 0);
      bfr[j][1] = ldfrag(B0, 4 * j + wc, 1);
    }
    if (kt + 1 < 32) stage(&lA[b ^ 1][1][0], Ag + (size_t)128 * D_MOD + (size_t)(kt + 1) * 64);
    asm volatile("" ::: "memory");
    __builtin_amdgcn_s_barrier();
    __builtin_amdgcn_s_setprio(1);
#pragma unroll
    for (int i = 0; i < 4; ++i)
#pragma unroll
      for (int j = 0; j < 2; ++j) {
        acc[i][j] = __builtin_amdgcn_mfma_f32_16x16x32_bf16(bfr[j][0], af[i][0], acc[i][j], 0, 0, 0);
        acc[i][j] = __builtin_amdgcn_mfma_f32_16x16x32_bf16(bfr[j][1], af[i][1], acc[i][j], 0, 0, 0);
      }
    __builtin_amdgcn_s_setprio(0);
    asm volatile("" ::: "memory");
    __builtin_amdgcn_s_barrier();
    asm volatile("" ::: "memory");
    // ---- phase 1
#pragma unroll
    for (int j = 2; j < 4; ++j) {
      bfr[j][0] = ldfrag(B1, 4 * j + wc - 8, 0);
      bfr[j][1] = ldfrag(B1, 4 * j + wc - 8, 1);
    }
    if (kt + 2 < 32) stage(&lA[b][0][0], Ag + (size_t)(kt + 2) * 64);
    asm volatile("" ::: "memory");
    __builtin_amdgcn_s_barrier();
    __builtin_amdgcn_s_setprio(1);
#pragma unroll
    for (int i = 0; i < 4; ++i)
#pragma unroll
      for (int j = 2; j < 4; ++j) {
        acc[i][j] = __builtin_amdgcn_mfma_f32_16x16x32_bf16(bfr[j][0], af[i][0], acc[i][j], 0, 0, 0);
        acc[i][j] = __builtin_amdgcn_mfma_f32_16x16x32_bf16(bfr[j][1], af[i][1], acc[i][j], 0, 0, 0);
      }
    __builtin_amdgcn_s_setprio(0);
    asm volatile("" ::: "memory");
    __builtin_amdgcn_s_barrier();
    asm volatile("" ::: "memory");
    // ---- phase 2
#pragma unroll
    for (int i = 0; i < 4; ++i) {
      af[i][0] = ldfrag(A1, 2 * i + wr, 0);
      af[i][1] = ldfrag(A1, 2 * i + wr, 1);
    }
    if (kt + 2 < 32) stage(&lB[b][0][0], Bg + (size_t)(kt + 2) * 64);
    asm volatile("" ::: "memory");
    __builtin_amdgcn_s_barrier();
    __builtin_amdgcn_s_setprio(1);
#pragma unroll
    for (int i = 0; i < 4; ++i)
#pragma unroll
      for (int j = 0; j < 2; ++j) {
        acc[i + 4][j] = __builtin_amdgcn_mfma_f32_16x16x32_bf16(bfr[j][0], af[i][0], acc[i + 4][j], 0, 0, 0);
        acc[i + 4][j] = __builtin_amdgcn_mfma_f32_16x16x32_bf16(bfr[j][1], af[i][1], acc[i + 4][j], 0, 0, 0);
      }
    __builtin_amdgcn_s_setprio(0);
    asm volatile("" ::: "memory");
    __builtin_amdgcn_s_barrier();
    asm volatile("" ::: "memory");
    // ---- phase 3
    if (kt + 2 < 32) stage(&lB[b][1][0], Bg + (size_t)128 * D_MOD + (size_t)(kt + 2) * 64);
    asm volatile("" ::: "memory");
    __builtin_amdgcn_s_barrier();
    __builtin_amdgcn_s_setprio(1);
#pragma unroll
    for (int i = 0; i < 4; ++i)
#pragma unroll
      for (int j = 2; j < 4; ++j) {
        acc[i + 4][j] = __builtin_amdgcn_mfma_f32_16x16x32_bf16(bfr[j][0], af[i][0], acc[i + 4][j], 0, 0, 0);
        acc[i + 4][j] = __builtin_amdgcn_mfma_f32_16x16x32_bf16(bfr[j][1], af[i][1], acc[i + 4][j], 0, 0, 0);
      }
    __builtin_amdgcn_s_setprio(0);
    if (kt == 30) asm volatile("s_waitcnt vmcnt(0)" ::: "memory");
    else          asm volatile("s_waitcnt vmcnt(6)" ::: "memory");
    __builtin_amdgcn_s_barrier();
    asm volatile("" ::: "memory");
  }

#pragma unroll
  for (int i = 0; i < 8; ++i) {
    int row = tm * 256 + (2 * i + wr) * 16 + l16;
#pragma unroll
    for (int j = 0; j < 4; ++j) {
      int col = tn * 256 + (4 * j + wc) * 16 + q * 4;
      ushort4 o;
      o.x = f2bf_bits(acc[i][j][0]); o.y = f2bf_bits(acc[i][j][1]);
      o.z = f2bf_bits(acc[i][j][2]); o.w = f2bf_bits(acc[i][j][3]);
      *(ushort4*)&encb[(size_t)row * D_MOD + col] = o;
    }
  }
}

// ---------- GEMM 2: S = silu(enc_gathered @ U[e]^T) * (w*gamma) ----------
__global__ __launch_bounds__(256) void gemm_up(
    const unsigned short* __restrict__ encb,
    const unsigned short* __restrict__ Ub,
    const int* __restrict__ tile2e, const int* __restrict__ tok_row,
    const float* __restrict__ w_row,
    unsigned short* __restrict__ S) {
  const int rt = blockIdx.x;
  const int e = tile2e[rt];
  if (e < 0) return;
  __shared__ unsigned short lA[128 * 32], lB[128 * 32];
  const int tid = threadIdx.x;
  const int wv = tid >> 6, lane = tid & 63;
  const int q = lane >> 4, l16 = lane & 15;

  const int srow = wv * 16 + (lane >> 2);
  const int scol = (lane & 3) * 8;
  const int tok0 = tok_row[rt * 128 + srow];
  const int tok1 = tok_row[rt * 128 + srow + 64];
  const unsigned short* ga0 = encb + (size_t)tok0 * D_MOD + scol;
  const unsigned short* ga1 = encb + (size_t)tok1 * D_MOD + scol;
  const unsigned short* gbase = Ub + (size_t)e * R_RK * D_MOD;
  const unsigned short* gb0 = gbase + (size_t)srow * D_MOD + scol;
  const unsigned short* gb1 = gb0 + (size_t)64 * D_MOD;
  unsigned short* la0 = &lA[(wv * 16) * 32];
  unsigned short* la1 = &lA[(wv * 16 + 64) * 32];
  unsigned short* lb0 = &lB[(wv * 16) * 32];
  unsigned short* lb1 = &lB[(wv * 16 + 64) * 32];

  const int wm = (wv & 1) * 64, wn = (wv >> 1) * 64;
  f32x4 acc[4][4] = {};

  for (int k0 = 0; k0 < D_MOD; k0 += 32) {
    gl2lds16(ga0 + k0, la0);
    gl2lds16(ga1 + k0, la1);
    gl2lds16(gb0 + k0, lb0);
    gl2lds16(gb1 + k0, lb1);
    __syncthreads();
    bf16x8 af[4], bf[4];
#pragma unroll
    for (int i = 0; i < 4; i++) af[i] = *(const bf16x8*)&lA[(wm + i * 16 + l16) * 32 + q * 8];
#pragma unroll
    for (int j = 0; j < 4; j++) bf[j] = *(const bf16x8*)&lB[(wn + j * 16 + l16) * 32 + q * 8];
#pragma unroll
    for (int i = 0; i < 4; i++)
#pragma unroll
      for (int j = 0; j < 4; j++)
        acc[i][j] = __builtin_amdgcn_mfma_f32_16x16x32_bf16(bf[j], af[i], acc[i][j], 0, 0, 0);
    __syncthreads();
  }
#pragma unroll
  for (int i = 0; i < 4; i++) {
    int prow = rt * 128 + wm + i * 16 + l16;
    float wr = w_row[prow];
#pragma unroll
    for (int j = 0; j < 4; j++) {
      int col = wn + j * 16 + q * 4;
      ushort4 o;
      float v0 = acc[i][j][0], v1 = acc[i][j][1], v2 = acc[i][j][2], v3 = acc[i][j][3];
      o.x = f2bf_bits((v0 / (1.0f + __expf(-v0))) * wr);
      o.y = f2bf_bits((v1 / (1.0f + __expf(-v1))) * wr);
      o.z = f2bf_bits((v2 / (1.0f + __expf(-v2))) * wr);
      o.w = f2bf_bits((v3 / (1.0f + __expf(-v3))) * wr);
      *(ushort4*)&S[(size_t)prow * R_RK + col] = o;
    }
  }
}

// ---------- GEMM 3: Drows = S @ V[e]^T ----------
__global__ __launch_bounds__(256) void gemm_down(
    const unsigned short* __restrict__ S,
    const unsigned short* __restrict__ Vb,
    const int* __restrict__ tile2e,
    unsigned short* __restrict__ Drows) {
  const int rt = blockIdx.x, ct = blockIdx.y;
  const int e = tile2e[rt];
  if (e < 0) return;
  __shared__ unsigned short lA[128 * 32], lB[128 * 32];
  const int tid = threadIdx.x;
  const int wv = tid >> 6, lane = tid & 63;
  const int q = lane >> 4, l16 = lane & 15;

  const int srow = wv * 16 + (lane >> 2);
  const int scol = (lane & 3) * 8;
  const unsigned short* ga0 = S + (size_t)(rt * 128 + srow) * R_RK + scol;
  const unsigned short* ga1 = ga0 + (size_t)64 * R_RK;
  const unsigned short* gb0 = Vb + ((size_t)e * D_MOD + ct * 128 + srow) * R_RK + scol;
  const unsigned short* gb1 = gb0 + (size_t)64 * R_RK;
  unsigned short* la0 = &lA[(wv * 16) * 32];
  unsigned short* la1 = &lA[(wv * 16 + 64) * 32];
  unsigned short* lb0 = &lB[(wv * 16) * 32];
  unsigned short* lb1 = &lB[(wv * 16 + 64) * 32];

  const int wm = (wv & 1) * 64, wn = (wv >> 1) * 64;
  f32x4 acc[4][4] = {};

  for (int k0 = 0; k0 < R_RK; k0 += 32) {
    gl2lds16(ga0 + k0, la0);
    gl2lds16(ga1 + k0, la1);
    gl2lds16(gb0 + k0, lb0);
    gl2lds16(gb1 + k0, lb1);
    __syncthreads();
    bf16x8 af[4], bf[4];
#pragma unroll
    for (int i = 0; i < 4; i++) af[i] = *(const bf16x8*)&lA[(wm + i * 16 + l16) * 32 + q * 8];
#pragma unroll
    for (int j = 0; j < 4; j++) bf[j] = *(const bf16x8*)&lB[(wn + j * 16 + l16) * 32 + q * 8];
#pragma unroll
    for (int i = 0; i < 4; i++)
#pragma unroll
      for (int j = 0; j < 4; j++)
        acc[i][j] = __builtin_amdgcn_mfma_f32_16x16x32_bf16(bf[j], af[i], acc[i][j], 0, 0, 0);
    __syncthreads();
  }
#pragma unroll
  for (int i = 0; i < 4; i++) {
    int prow = rt * 128 + wm + i * 16 + l16;
    size_t obase = (size_t)prow * D_MOD + ct * 128 + wn;
#pragma unroll
    for (int j = 0; j < 4; j++) {
      ushort4 o;
      o.x = f2bf_bits(acc[i][j][0]); o.y = f2bf_bits(acc[i][j][1]);
      o.z = f2bf_bits(acc[i][j][2]); o.w = f2bf_bits(acc[i][j][3]);
      *(ushort4*)&Drows[obase + j * 16 + q * 4] = o;
    }
  }
}

// ---------- gather: out[b] = enc[b] + Drows[pos(b,0)] + Drows[pos(b,1)] ----------
__global__ __launch_bounds__(256) void gather_kernel(
    const unsigned short* __restrict__ encb, const unsigned short* __restrict__ Drows,
    const int* __restrict__ pos, float* __restrict__ out) {
  int b = blockIdx.x;
  int t = threadIdx.x;
  int p0 = pos[b * 2], p1 = pos[b * 2 + 1];
  u16x8 e8 = *(const u16x8*)(encb + (size_t)b * D_MOD + t * 8);
  u16x8 d0 = *(const u16x8*)(Drows + (size_t)p0 * D_MOD + t * 8);
  u16x8 d1 = *(const u16x8*)(Drows + (size_t)p1 * D_MOD + t * 8);
  float o[8];
#pragma unroll
  for (int k = 0; k < 8; k++) o[k] = bf2f(e8[k]) + bf2f(d0[k]) + bf2f(d1[k]);
  float4* op = (float4*)(out + (size_t)b * D_MOD + t * 8);
  op[0] = make_float4(o[0], o[1], o[2], o[3]);
  op[1] = make_float4(o[4], o[5], o[6], o[7]);
}

// ---------- launch ----------
extern "C" void kernel_launch(void* const* d_in, const int* in_sizes, int n_in,
                              void* d_out, int out_size, void* d_ws, size_t ws_size,
                              hipStream_t stream) {
  const float* x    = (const float*)d_in[0];
  const float* Wenc = (const float*)d_in[1];
  const float* benc = (const float*)d_in[2];
  const float* Wg   = (const float*)d_in[3];
  const float* U    = (const float*)d_in[4];
  const float* V    = (const float*)d_in[5];
  const float* gamma= (const float*)d_in[6];
  float* out = (float*)d_out;

  char* ws = (char*)d_ws;
  size_t off = 0;
  auto alloc = [&](size_t bytes) { size_t o = off; off = (off + bytes + 255) & ~(size_t)255; return o; };
  unsigned short* xb    = (unsigned short*)(ws + alloc((size_t)B_TOK * D_MOD * 2));
  unsigned short* Wencb = (unsigned short*)(ws + alloc((size_t)D_MOD * D_MOD * 2));
  unsigned short* encb  = (unsigned short*)(ws + alloc((size_t)B_TOK * D_MOD * 2));
  unsigned short* Ub    = (unsigned short*)(ws + alloc((size_t)N_EXP * R_RK * D_MOD * 2));
  unsigned short* Vb    = (unsigned short*)(ws + alloc((size_t)N_EXP * D_MOD * R_RK * 2));
  float*  WgEffF = (float*)(ws + alloc((size_t)N_EXP * D_MOD * 4));
  double* part  = (double*)(ws + alloc((size_t)32 * N_EXP * D_MOD * 8));
  double* biasd = (double*)(ws + alloc(N_EXP * 8));
  int* counts   = (int*)(ws + alloc(64));
  int* cursor   = (int*)(ws + alloc(64));
  int* tile2e   = (int*)(ws + alloc(MAXTILES * 4));
  int* tke      = (int*)(ws + alloc((size_t)B_TOK * 2 * 4));
  float* tkw    = (float*)(ws + alloc((size_t)B_TOK * 2 * 4));
  int* pos      = (int*)(ws + alloc((size_t)B_TOK * 2 * 4));
  int* tok_row  = (int*)(ws + alloc((size_t)MAXROWS * 4));
  float* w_row  = (float*)(ws + alloc((size_t)MAXROWS * 4));
  unsigned short* S = (unsigned short*)(ws + alloc((size_t)MAXROWS * R_RK * 2));
  unsigned short* Drows = (unsigned short*)(ws + alloc((size_t)MAXROWS * D_MOD * 2));
  (void)ws_size; (void)in_sizes; (void)n_in; (void)out_size;

  init_kernel<<<(MAXROWS + 255) / 256, 256, 0, stream>>>(counts, tok_row, w_row);

  int cvt_total = CVT_N1 + CVT_N2 + CVT_N3;
  cvt_all<<<(cvt_total + 255) / 256, 256, 0, stream>>>(Wenc, U, V, Wencb, Ub, Vb);

  wgeff_partial<<<dim3(8, 32), 256, 0, stream>>>(Wg, Wenc, part);
  wgeff_reduce<<<dim3(8, N_EXP), 256, 0, stream>>>(part, WgEffF);
  bias_kernel<<<N_EXP, 256, 0, stream>>>(benc, Wg, biasd);

  routing_kernel<<<B_TOK / 32, 1024, 0, stream>>>(x, WgEffF, biasd, tke, tkw, xb);
  hist_kernel<<<(B_TOK * 2 + 1023) / 1024, 1024, 0, stream>>>(tke, counts);
  bases_kernel<<<1, 64, 0, stream>>>(counts, cursor, tile2e);
  scatter_kernel<<<B_TOK / 256, 256, 0, stream>>>(tke, tkw, gamma, cursor, tok_row, w_row, pos);

  gemm_enc<<<(B_TOK / 256) * (D_MOD / 256), 512, 0, stream>>>(xb, Wencb, encb);
  gemm_up<<<MAXTILES, 256, 0, stream>>>(encb, Ub, tile2e, tok_row, w_row, S);
  gemm_down<<<dim3(MAXTILES, D_MOD / 128), 256, 0, stream>>>(S, Vb, tile2e, Drows);
  gather_kernel<<<B_TOK, 256, 0, stream>>>(encb, Drows, pos, out);
}